// Round 9
// baseline (729.798 us; speedup 1.0000x reference)
//
#include <hip/hip_runtime.h>
#include <hip/hip_cooperative_groups.h>
#include <math.h>

namespace cg = cooperative_groups;

// B=32, D=2048 rank-1 self-attention, fp32.
//   k2_j = k_j*log2e ; m2_j = k2_j>=0 ? k2_j*qmax : k2_j*qmin
//   Z_j  = sum_i 2^(q_i k2_j - m2_j) ; d_j = log2(|v_j|/Z_j) - m2_j
//   out_i = sum_{j:v>0} 2^(fma(q_i,k2_j,d_j)) - sum_{j:v<0} 2^(...)
//
// R9: single cooperative kernel (grid 1536x256, exactly max co-residency at
// launch_bounds(256,6)): phase1 = R8 k1 (bf16 MFMA, splitK=4), grid.sync,
// phase2 = Z/d/partition on 1024 blocks (32b x 32 j-chunks of 64, SEG=68),
// grid.sync, phase3 = out on 1024 blocks. Removes 2 launch gaps and makes
// the whole pipeline ONE dispatch -> visible in rocprof top-5 (R8 was blind:
// top-5 all harness fills). Fallback to the proven 3-kernel path if the
// cooperative launch is rejected (checked return code, deterministic).

#define D 2048
#define BATCH 32

#define PART_STRIDE 196608   // one splitK part: 3*65536 (m*65536 + b*D + row)
#define L2E 1.4426950408889634f

// fused-kernel kdp layout: 32 b * 32 segs * 68 slots
#define SEGF 68
#define KDPF_OFF 786432      // floats: 32*32*68 float2 = 139264 floats
#define NPF_OFF  925696      // 1024 ints

// fallback (R8) kdp layout: 32 b * 16 segs * 132 slots
#define SEG 132
#define KDP_OFF 786432       // floats: 32*16*132 float2 = 135168 floats
#define NP_OFF  921600       // 512 ints

typedef short s16x8 __attribute__((ext_vector_type(8)));
typedef float f32x4 __attribute__((ext_vector_type(4)));

union FragU { s16x8 v; unsigned u[4]; };

__device__ __forceinline__ float fast_exp2(float x) {
#if __has_builtin(__builtin_amdgcn_exp2f)
  return __builtin_amdgcn_exp2f(x);
#else
  return exp2f(x);
#endif
}
// pack two fp32 into one VGPR of two RNE-rounded bf16
__device__ __forceinline__ unsigned pack_rne(float a, float b) {
  unsigned ua = __float_as_uint(a), ub = __float_as_uint(b);
  ua = ua + 0x7FFFu + ((ua >> 16) & 1u);
  ub = ub + 0x7FFFu + ((ub >> 16) & 1u);
  return (ua >> 16) | (ub & 0xFFFF0000u);
}
__device__ __forceinline__ void pack8(const float4& fa, const float4& fb,
                                      FragU& h) {
  h.u[0] = pack_rne(fa.x, fa.y);
  h.u[1] = pack_rne(fa.z, fa.w);
  h.u[2] = pack_rne(fb.x, fb.y);
  h.u[3] = pack_rne(fb.z, fb.w);
}

// ==================== fused cooperative kernel ====================
__global__ __launch_bounds__(256, 6) void fused(
    const float* __restrict__ x, const float* __restrict__ Wq,
    const float* __restrict__ Wk, const float* __restrict__ Wv,
    const float* __restrict__ bq, const float* __restrict__ bk,
    const float* __restrict__ bv, float* __restrict__ ws,
    float* __restrict__ out) {
  __shared__ __align__(16) unsigned char smem[18944];
  cg::grid_group grid = cg::this_grid();
  const int tid = threadIdx.x;
  const int bx = blockIdx.x;
  const int lane = tid & 63, wv4 = tid >> 6;

  // ---------- phase 1: projections (all 1536 blocks) ----------
  {
    float (*red)[512] = (float (*)[512])smem;
    const int tile = bx >> 2, kq = bx & 3;
    const int m = tile >> 7, lr = (tile & 127) * 16;
    const float* W = (m == 0) ? Wq : (m == 1) ? Wk : Wv;
    const int kbase = kq * 512 + wv4 * 128 + (lane >> 4) * 8;
    const float* ap = W + (size_t)(lr + (lane & 15)) * D + kbase;
    const float* xp0 = x + (size_t)(lane & 15) * D + kbase;
    const float* xp1 = xp0 + 16 * D;

    f32x4 acc0 = {0.f, 0.f, 0.f, 0.f}, acc1 = {0.f, 0.f, 0.f, 0.f};
#pragma unroll
    for (int s = 0; s < 4; ++s) {
      const int off = s * 32;
      float4 fa = *(const float4*)(ap + off);
      float4 fb = *(const float4*)(ap + off + 4);
      float4 x0a = *(const float4*)(xp0 + off);
      float4 x0b = *(const float4*)(xp0 + off + 4);
      float4 x1a = *(const float4*)(xp1 + off);
      float4 x1b = *(const float4*)(xp1 + off + 4);
      FragU Ah, Bh0, Bh1;
      pack8(fa, fb, Ah);
      pack8(x0a, x0b, Bh0);
      pack8(x1a, x1b, Bh1);
      acc0 = __builtin_amdgcn_mfma_f32_16x16x32_bf16(Ah.v, Bh0.v, acc0, 0, 0, 0);
      acc1 = __builtin_amdgcn_mfma_f32_16x16x32_bf16(Ah.v, Bh1.v, acc1, 0, 0, 0);
    }
    const int col = lane & 15, rq = (lane >> 4) * 4;
#pragma unroll
    for (int r = 0; r < 4; ++r) {
      red[wv4][col * 16 + rq + r] = acc0[r];
      red[wv4][(col + 16) * 16 + rq + r] = acc1[r];
    }
    __syncthreads();
    float* part = ws + (size_t)kq * PART_STRIDE + (size_t)m * 65536;
#pragma unroll
    for (int i = tid; i < 512; i += 256) {
      float s = (red[0][i] + red[1][i]) + (red[2][i] + red[3][i]);
      part[(size_t)(i >> 4) * D + lr + (i & 15)] = s;
    }
  }
  __threadfence();
  grid.sync();

  // ---------- phase 2: minmax + Z + finalize + partition (1024 blocks) -----
  if (bx < 1024) {
    float* qs = (float*)smem;            // 2048 floats
    float* zs = qs + 2048;               // 256
    float* rmx = zs + 256;               // 4
    float* rmn = rmx + 4;                // 4
    int* cnt = (int*)(rmn + 4);          // 2
    const int b = bx >> 5, jc = bx & 31;
    if (tid == 0) { cnt[0] = 0; cnt[1] = 0; }
    const size_t qb = (size_t)b * D;

    float mx = -1e30f, mn = 1e30f;
#pragma unroll
    for (int h = 0; h < 2; ++h) {
      const int idx = tid + h * 256;
      float4 p0 = ((const float4*)(ws + qb))[idx];
      float4 p1 = ((const float4*)(ws + PART_STRIDE + qb))[idx];
      float4 p2 = ((const float4*)(ws + 2 * PART_STRIDE + qb))[idx];
      float4 p3 = ((const float4*)(ws + 3 * PART_STRIDE + qb))[idx];
      float4 bb = ((const float4*)bq)[idx];
      float4 qv = {(p0.x + p1.x) + (p2.x + p3.x) + bb.x,
                   (p0.y + p1.y) + (p2.y + p3.y) + bb.y,
                   (p0.z + p1.z) + (p2.z + p3.z) + bb.z,
                   (p0.w + p1.w) + (p2.w + p3.w) + bb.w};
      *(float4*)&qs[idx * 4] = qv;
      mx = fmaxf(mx, fmaxf(fmaxf(qv.x, qv.y), fmaxf(qv.z, qv.w)));
      mn = fminf(mn, fminf(fminf(qv.x, qv.y), fminf(qv.z, qv.w)));
    }
#pragma unroll
    for (int off = 32; off; off >>= 1) {
      mx = fmaxf(mx, __shfl_down(mx, off));
      mn = fminf(mn, __shfl_down(mn, off));
    }
    if ((tid & 63) == 0) { rmx[tid >> 6] = mx; rmn[tid >> 6] = mn; }
    __syncthreads();
    mx = fmaxf(fmaxf(rmx[0], rmx[1]), fmaxf(rmx[2], rmx[3]));
    mn = fminf(fminf(rmn[0], rmn[1]), fminf(rmn[2], rmn[3]));

    const int jl = tid & 63, ih = tid >> 6;
    const int j = jc * 64 + jl;
    const size_t jo = 65536 + qb + j;
    const float k2 = ((ws[jo] + ws[PART_STRIDE + jo]) +
                      (ws[2 * PART_STRIDE + jo] + ws[3 * PART_STRIDE + jo]) +
                      bk[j]) * L2E;
    const float m2 = (k2 >= 0.f) ? k2 * mx : k2 * mn;
    const float nm2 = -m2;
    const float* qp = qs + ih * 512;
    float z0 = 0.f, z1 = 0.f, z2 = 0.f, z3 = 0.f;
#pragma unroll 8
    for (int i = 0; i < 512; i += 4) {
      float4 q4 = *(const float4*)&qp[i];  // wave-uniform -> LDS broadcast
      z0 += fast_exp2(fmaf(q4.x, k2, nm2));
      z1 += fast_exp2(fmaf(q4.y, k2, nm2));
      z2 += fast_exp2(fmaf(q4.z, k2, nm2));
      z3 += fast_exp2(fmaf(q4.w, k2, nm2));
    }
    zs[tid] = (z0 + z1) + (z2 + z3);
    __syncthreads();

    float2* kdp = (float2*)(ws + KDPF_OFF) + ((size_t)b * 32 + jc) * SEGF;
    if (tid < 64) {
      float Z = (zs[tid] + zs[tid + 64]) + (zs[tid + 128] + zs[tid + 192]);
      const size_t vo = 131072 + qb + j;
      float v = (ws[vo] + ws[PART_STRIDE + vo]) +
                (ws[2 * PART_STRIDE + vo] + ws[3 * PART_STRIDE + vo]) + bv[j];
      float d = __log2f(fabsf(v) / Z) - m2;  // v==0 -> -inf -> exp2 -> 0
      int slot;
      if (v >= 0.f) slot = atomicAdd(&cnt[0], 1);
      else          slot = (SEGF - 1) - atomicAdd(&cnt[1], 1);
      kdp[slot] = make_float2(k2, d);
    }
    __syncthreads();
    const int npos = cnt[0];
    if (tid < 4) kdp[npos + tid] = make_float2(0.f, -1e30f);  // pads: 0
    if (tid == 0) ((int*)(ws + NPF_OFF))[b * 32 + jc] = npos;
  }
  __threadfence();
  grid.sync();

  // ---------- phase 3: out (1024 blocks) ----------
  if (bx < 1024) {
    float2* kd = (float2*)smem;                 // 2176 float2 = 17408 B
    float* rs = (float*)(smem + 17408);         // 256 floats
    int* np = (int*)(smem + 18432);             // 32 ints
    const int b = bx >> 5, ic = bx & 31;

    const float4* src = (const float4*)((const float2*)(ws + KDPF_OFF) +
                                        (size_t)b * 32 * SEGF);
    for (int idx = tid; idx < (32 * SEGF) / 2; idx += 256)
      ((float4*)kd)[idx] = src[idx];
    if (tid < 32) np[tid] = ((const int*)(ws + NPF_OFF))[b * 32 + tid];

    const int il = tid & 63, jh = tid >> 6;
    const int i = ic * 64 + il;
    const size_t io = (size_t)b * D + i;
    const float qi = (ws[io] + ws[PART_STRIDE + io]) +
                     (ws[2 * PART_STRIDE + io] + ws[3 * PART_STRIDE + io]) +
                     bq[i];
    __syncthreads();

    float p0 = 0.f, p1 = 0.f, p2 = 0.f, p3 = 0.f;
    float n0 = 0.f, n1 = 0.f, n2 = 0.f, n3 = 0.f;
#pragma unroll
    for (int s = jh * 8; s < jh * 8 + 8; ++s) {
      const float2* seg = kd + s * SEGF;
      const int npos = np[s];
      const int pe = (npos + 3) & ~3;      // pads beyond npos contribute 0
      const int ns = (npos + 4) & ~3;      // re-touched pads contribute 0
      for (int jj = 0; jj < pe; jj += 4) {
        float4 t0 = *(const float4*)&seg[jj];
        float4 t1 = *(const float4*)&seg[jj + 2];
        p0 += fast_exp2(fmaf(qi, t0.x, t0.y));
        p1 += fast_exp2(fmaf(qi, t0.z, t0.w));
        p2 += fast_exp2(fmaf(qi, t1.x, t1.y));
        p3 += fast_exp2(fmaf(qi, t1.z, t1.w));
      }
      for (int jj = ns; jj < SEGF; jj += 4) {
        float4 t0 = *(const float4*)&seg[jj];
        float4 t1 = *(const float4*)&seg[jj + 2];
        n0 += fast_exp2(fmaf(qi, t0.x, t0.y));
        n1 += fast_exp2(fmaf(qi, t0.z, t0.w));
        n2 += fast_exp2(fmaf(qi, t1.x, t1.y));
        n3 += fast_exp2(fmaf(qi, t1.z, t1.w));
      }
    }
    rs[tid] = ((p0 + p1) + (p2 + p3)) - ((n0 + n1) + (n2 + n3));
    __syncthreads();
    if (tid < 64)
      out[(size_t)b * D + ic * 64 + tid] =
          (rs[tid] + rs[tid + 64]) + (rs[tid + 128] + rs[tid + 192]);
  }
}

// ==================== fallback: proven R8 3-kernel path ====================
__global__ __launch_bounds__(256, 4) void k1_proj(
    const float* __restrict__ x, const float* __restrict__ Wq,
    const float* __restrict__ Wk, const float* __restrict__ Wv,
    float* __restrict__ ws) {
  __shared__ float red[4][512];
  const int tid = threadIdx.x;
  const int lane = tid & 63, wv = tid >> 6;
  const int tile = blockIdx.x >> 2, kq = blockIdx.x & 3;
  const int m = tile >> 7, lr = (tile & 127) * 16;
  const float* W = (m == 0) ? Wq : (m == 1) ? Wk : Wv;

  const int kbase = kq * 512 + wv * 128 + (lane >> 4) * 8;
  const float* ap = W + (size_t)(lr + (lane & 15)) * D + kbase;
  const float* xp0 = x + (size_t)(lane & 15) * D + kbase;
  const float* xp1 = xp0 + 16 * D;

  f32x4 acc0 = {0.f, 0.f, 0.f, 0.f}, acc1 = {0.f, 0.f, 0.f, 0.f};
#pragma unroll
  for (int s = 0; s < 4; ++s) {
    const int off = s * 32;
    float4 fa = *(const float4*)(ap + off);
    float4 fb = *(const float4*)(ap + off + 4);
    float4 x0a = *(const float4*)(xp0 + off);
    float4 x0b = *(const float4*)(xp0 + off + 4);
    float4 x1a = *(const float4*)(xp1 + off);
    float4 x1b = *(const float4*)(xp1 + off + 4);
    FragU Ah, Bh0, Bh1;
    pack8(fa, fb, Ah);
    pack8(x0a, x0b, Bh0);
    pack8(x1a, x1b, Bh1);
    acc0 = __builtin_amdgcn_mfma_f32_16x16x32_bf16(Ah.v, Bh0.v, acc0, 0, 0, 0);
    acc1 = __builtin_amdgcn_mfma_f32_16x16x32_bf16(Ah.v, Bh1.v, acc1, 0, 0, 0);
  }
  const int col = lane & 15, rq = (lane >> 4) * 4;
#pragma unroll
  for (int r = 0; r < 4; ++r) {
    red[wv][col * 16 + rq + r] = acc0[r];
    red[wv][(col + 16) * 16 + rq + r] = acc1[r];
  }
  __syncthreads();
  float* part = ws + (size_t)kq * PART_STRIDE + (size_t)m * 65536;
#pragma unroll
  for (int i = tid; i < 512; i += 256) {
    float s = (red[0][i] + red[1][i]) + (red[2][i] + red[3][i]);
    part[(size_t)(i >> 4) * D + lr + (i & 15)] = s;
  }
}

__global__ __launch_bounds__(512, 4) void k3_dz(float* __restrict__ ws,
                                                const float* __restrict__ bq,
                                                const float* __restrict__ bk,
                                                const float* __restrict__ bv) {
  __shared__ float qs[2048];
  __shared__ float zs[512];
  __shared__ float rmx[8], rmn[8];
  __shared__ int cnt[2];
  const int bx = blockIdx.x, t = threadIdx.x;
  const int b = bx >> 4, jc = bx & 15;
  if (t == 0) { cnt[0] = 0; cnt[1] = 0; }

  const size_t qb = (size_t)b * D;
  float4 p0 = ((const float4*)(ws + qb))[t];
  float4 p1 = ((const float4*)(ws + PART_STRIDE + qb))[t];
  float4 p2 = ((const float4*)(ws + 2 * PART_STRIDE + qb))[t];
  float4 p3 = ((const float4*)(ws + 3 * PART_STRIDE + qb))[t];
  float4 bb = ((const float4*)bq)[t];
  float4 qv = {(p0.x + p1.x) + (p2.x + p3.x) + bb.x,
               (p0.y + p1.y) + (p2.y + p3.y) + bb.y,
               (p0.z + p1.z) + (p2.z + p3.z) + bb.z,
               (p0.w + p1.w) + (p2.w + p3.w) + bb.w};
  *(float4*)&qs[t * 4] = qv;
  float mx = fmaxf(fmaxf(qv.x, qv.y), fmaxf(qv.z, qv.w));
  float mn = fminf(fminf(qv.x, qv.y), fminf(qv.z, qv.w));
#pragma unroll
  for (int off = 32; off; off >>= 1) {
    mx = fmaxf(mx, __shfl_down(mx, off));
    mn = fminf(mn, __shfl_down(mn, off));
  }
  if ((t & 63) == 0) { rmx[t >> 6] = mx; rmn[t >> 6] = mn; }
  __syncthreads();
  mx = rmx[0]; mn = rmn[0];
#pragma unroll
  for (int w = 1; w < 8; ++w) {
    mx = fmaxf(mx, rmx[w]);
    mn = fminf(mn, rmn[w]);
  }

  const int jl = t & 127, ih = t >> 7;
  const int j = jc * 128 + jl;
  const size_t jo = 65536 + qb + j;
  const float k2 = ((ws[jo] + ws[PART_STRIDE + jo]) +
                    (ws[2 * PART_STRIDE + jo] + ws[3 * PART_STRIDE + jo]) +
                    bk[j]) * L2E;
  const float m2 = (k2 >= 0.f) ? k2 * mx : k2 * mn;
  const float nm2 = -m2;
  const float* qp = qs + ih * 512;
  float z0 = 0.f, z1 = 0.f, z2 = 0.f, z3 = 0.f;
#pragma unroll 8
  for (int i = 0; i < 512; i += 4) {
    float4 q4 = *(const float4*)&qp[i];
    z0 += fast_exp2(fmaf(q4.x, k2, nm2));
    z1 += fast_exp2(fmaf(q4.y, k2, nm2));
    z2 += fast_exp2(fmaf(q4.z, k2, nm2));
    z3 += fast_exp2(fmaf(q4.w, k2, nm2));
  }
  zs[t] = (z0 + z1) + (z2 + z3);
  __syncthreads();

  float2* kdp = (float2*)(ws + KDP_OFF) + ((size_t)b * 16 + jc) * SEG;
  if (t < 128) {
    float Z = (zs[t] + zs[t + 128]) + (zs[t + 256] + zs[t + 384]);
    const size_t vo = 131072 + qb + j;
    float v = (ws[vo] + ws[PART_STRIDE + vo]) +
              (ws[2 * PART_STRIDE + vo] + ws[3 * PART_STRIDE + vo]) + bv[j];
    float d = __log2f(fabsf(v) / Z) - m2;
    int slot;
    if (v >= 0.f) slot = atomicAdd(&cnt[0], 1);
    else          slot = (SEG - 1) - atomicAdd(&cnt[1], 1);
    kdp[slot] = make_float2(k2, d);
  }
  __syncthreads();
  const int npos = cnt[0];
  if (t < 4) kdp[npos + t] = make_float2(0.f, -1e30f);
  if (t == 0) ((int*)(ws + NP_OFF))[b * 16 + jc] = npos;
}

__global__ __launch_bounds__(512, 4) void k4_out(const float* __restrict__ ws,
                                                 const float* __restrict__ bq,
                                                 float* __restrict__ out) {
  __shared__ float2 kd[16 * SEG];
  __shared__ int np[16];
  __shared__ float rs[512];
  const int bx = blockIdx.x, t = threadIdx.x;
  const int b = bx >> 4, ic = bx & 15;

  const float4* src = (const float4*)((const float2*)(ws + KDP_OFF) +
                                      (size_t)b * 16 * SEG);
  for (int idx = t; idx < (16 * SEG) / 2; idx += 512)
    ((float4*)kd)[idx] = src[idx];
  if (t < 16) np[t] = ((const int*)(ws + NP_OFF))[b * 16 + t];

  const int il = t & 127, jh = t >> 7;
  const int i = ic * 128 + il;
  const size_t io = (size_t)b * D + i;
  const float qi = (ws[io] + ws[PART_STRIDE + io]) +
                   (ws[2 * PART_STRIDE + io] + ws[3 * PART_STRIDE + io]) +
                   bq[i];
  __syncthreads();

  float p0 = 0.f, p1 = 0.f, p2 = 0.f, p3 = 0.f;
  float n0 = 0.f, n1 = 0.f, n2 = 0.f, n3 = 0.f;
#pragma unroll
  for (int s = jh * 4; s < jh * 4 + 4; ++s) {
    const float2* seg = kd + s * SEG;
    const int npos = np[s];
    const int pe = (npos + 3) & ~3;
    const int ns = (npos + 4) & ~3;
    for (int jj = 0; jj < pe; jj += 4) {
      float4 t0 = *(const float4*)&seg[jj];
      float4 t1 = *(const float4*)&seg[jj + 2];
      p0 += fast_exp2(fmaf(qi, t0.x, t0.y));
      p1 += fast_exp2(fmaf(qi, t0.z, t0.w));
      p2 += fast_exp2(fmaf(qi, t1.x, t1.y));
      p3 += fast_exp2(fmaf(qi, t1.z, t1.w));
    }
    for (int jj = ns; jj < SEG; jj += 4) {
      float4 t0 = *(const float4*)&seg[jj];
      float4 t1 = *(const float4*)&seg[jj + 2];
      n0 += fast_exp2(fmaf(qi, t0.x, t0.y));
      n1 += fast_exp2(fmaf(qi, t0.z, t0.w));
      n2 += fast_exp2(fmaf(qi, t1.x, t1.y));
      n3 += fast_exp2(fmaf(qi, t1.z, t1.w));
    }
  }
  rs[t] = ((p0 + p1) + (p2 + p3)) - ((n0 + n1) + (n2 + n3));
  __syncthreads();
  if (t < 128)
    out[io] = (rs[il] + rs[il + 128]) + (rs[il + 256] + rs[il + 384]);
}

extern "C" void kernel_launch(void* const* d_in, const int* in_sizes, int n_in,
                              void* d_out, int out_size, void* d_ws, size_t ws_size,
                              hipStream_t stream) {
  (void)in_sizes; (void)n_in; (void)out_size; (void)ws_size;
  const float* x  = (const float*)d_in[0];
  const float* Wq = (const float*)d_in[1];
  const float* bq = (const float*)d_in[2];
  const float* Wk = (const float*)d_in[3];
  const float* bk = (const float*)d_in[4];
  const float* Wv = (const float*)d_in[5];
  const float* bv = (const float*)d_in[6];
  float* ws  = (float*)d_ws;
  float* out = (float*)d_out;

  void* args[] = {(void*)&x,  (void*)&Wq, (void*)&Wk, (void*)&Wv,
                  (void*)&bq, (void*)&bk, (void*)&bv, (void*)&ws, (void*)&out};
  hipError_t e = hipLaunchCooperativeKernel((void*)fused, dim3(1536),
                                            dim3(256), args, 0, stream);
  if (e != hipSuccess) {
    // deterministic fallback: proven R8 3-kernel path
    k1_proj<<<1536, 256, 0, stream>>>(x, Wq, Wk, Wv, ws);
    k3_dz<<<512, 512, 0, stream>>>(ws, bq, bk, bv);
    k4_out<<<512, 512, 0, stream>>>(ws, bq, out);
  }
}

// Round 10
// 144.310 us; speedup vs baseline: 5.0572x; 5.0572x over previous
//
#include <hip/hip_runtime.h>
#include <math.h>

// B=32, D=2048 rank-1 self-attention, fp32.
//   k2_j = k_j*log2e ; m2_j = k2_j>=0 ? k2_j*qmax : k2_j*qmin
//   Z_j  = sum_i 2^(q_i k2_j - m2_j) ; d_j = log2(|v_j|/Z_j) - m2_j
//   out_i = sum_{j:v>0} 2^(fma(q_i,k2_j,d_j)) - sum_{j:v<0} 2^(...)
//
// R10: revert R9's cooperative fusion (grid.sync ~300us each on 8 XCDs —
// measured: fused kernel 677us, VALUBusy 5% => ~34us real work, rest sync).
// Back to R8's 3-kernel path with ONE change: k1 splitK 4->8 (grid 3072,
// 12 blocks/CU queued) to hide the W-stream latency (R3 measured this
// structure at 1.35 TB/s effective; half of W is L3-warm per R9 FETCH).
// Readers sum 8 partials + bias. Nothing needs pre-zeroing, no atomics.

#define D 2048
#define BATCH 32
#define SEG 132       // kdp segment: 128 entries + 4 pad slots
#define NPART 8

// workspace float offsets
#define PART_STRIDE 196608     // one splitK part: 3*65536 (m*65536 + b*D + r)
#define KDP_OFF 1572864        // 8*196608; 32 b * 16 segs * 132 float2
#define NP_OFF  1708032        // KDP_OFF + 135168; 512 ints

#define L2E 1.4426950408889634f

typedef short s16x8 __attribute__((ext_vector_type(8)));
typedef float f32x4 __attribute__((ext_vector_type(4)));

union FragU { s16x8 v; unsigned u[4]; };

__device__ __forceinline__ float fast_exp2(float x) {
#if __has_builtin(__builtin_amdgcn_exp2f)
  return __builtin_amdgcn_exp2f(x);
#else
  return exp2f(x);
#endif
}
// pack two fp32 into one VGPR of two RNE-rounded bf16
__device__ __forceinline__ unsigned pack_rne(float a, float b) {
  unsigned ua = __float_as_uint(a), ub = __float_as_uint(b);
  ua = ua + 0x7FFFu + ((ua >> 16) & 1u);
  ub = ub + 0x7FFFu + ((ub >> 16) & 1u);
  return (ua >> 16) | (ub & 0xFFFF0000u);
}
__device__ __forceinline__ void pack8(const float4& fa, const float4& fb,
                                      FragU& h) {
  h.u[0] = pack_rne(fa.x, fa.y);
  h.u[1] = pack_rne(fa.z, fa.w);
  h.u[2] = pack_rne(fb.x, fb.y);
  h.u[3] = pack_rne(fb.z, fb.w);
}
// sum the 8 splitK partials at float offset o
__device__ __forceinline__ float sum_parts(const float* __restrict__ ws,
                                           size_t o) {
  float s0 = ws[o] + ws[o + PART_STRIDE];
  float s1 = ws[o + 2 * PART_STRIDE] + ws[o + 3 * PART_STRIDE];
  float s2 = ws[o + 4 * PART_STRIDE] + ws[o + 5 * PART_STRIDE];
  float s3 = ws[o + 6 * PART_STRIDE] + ws[o + 7 * PART_STRIDE];
  return (s0 + s1) + (s2 + s3);
}

// ---------------- K1: projections via LDS-free bf16 MFMA ----------------
// grid 3072 = 384 row-tiles(16 rows) x 8 K-eighths. 4 waves/block, wave wv
// covers K [ke*256 + wv*64, +64), 2 steps of 32. A-frag = 8 consecutive
// fp32 of W per lane (row = lr+(lane&15), k += (lane>>4)*8); B-frags = 8
// consecutive fp32 of x (batch = lane&15 / +16). RNE bf16, 2 MFMAs/step.
// LDS reduce across the 4 waves, plain store to part buffer ke.
__global__ __launch_bounds__(256, 4) void k1_proj(
    const float* __restrict__ x, const float* __restrict__ Wq,
    const float* __restrict__ Wk, const float* __restrict__ Wv,
    float* __restrict__ ws) {
  __shared__ float red[4][512];
  const int tid = threadIdx.x;
  const int lane = tid & 63, wv = tid >> 6;
  const int tile = blockIdx.x >> 3, ke = blockIdx.x & 7;
  const int m = tile >> 7, lr = (tile & 127) * 16;
  const float* W = (m == 0) ? Wq : (m == 1) ? Wk : Wv;

  const int kbase = ke * 256 + wv * 64 + (lane >> 4) * 8;
  const float* ap = W + (size_t)(lr + (lane & 15)) * D + kbase;
  const float* xp0 = x + (size_t)(lane & 15) * D + kbase;
  const float* xp1 = xp0 + 16 * D;

  f32x4 acc0 = {0.f, 0.f, 0.f, 0.f}, acc1 = {0.f, 0.f, 0.f, 0.f};
#pragma unroll
  for (int s = 0; s < 2; ++s) {
    const int off = s * 32;
    float4 fa = *(const float4*)(ap + off);
    float4 fb = *(const float4*)(ap + off + 4);
    float4 x0a = *(const float4*)(xp0 + off);
    float4 x0b = *(const float4*)(xp0 + off + 4);
    float4 x1a = *(const float4*)(xp1 + off);
    float4 x1b = *(const float4*)(xp1 + off + 4);
    FragU Ah, Bh0, Bh1;
    pack8(fa, fb, Ah);
    pack8(x0a, x0b, Bh0);
    pack8(x1a, x1b, Bh1);
    acc0 = __builtin_amdgcn_mfma_f32_16x16x32_bf16(Ah.v, Bh0.v, acc0, 0, 0, 0);
    acc1 = __builtin_amdgcn_mfma_f32_16x16x32_bf16(Ah.v, Bh1.v, acc1, 0, 0, 0);
  }
  // C/D: col = lane&15 (batch), row = (lane>>4)*4 + reg (weight row)
  const int col = lane & 15, rq = (lane >> 4) * 4;
#pragma unroll
  for (int r = 0; r < 4; ++r) {
    red[wv][col * 16 + rq + r] = acc0[r];
    red[wv][(col + 16) * 16 + rq + r] = acc1[r];
  }
  __syncthreads();
  float* part = ws + (size_t)ke * PART_STRIDE + (size_t)m * 65536;
#pragma unroll
  for (int i = tid; i < 512; i += 256) {
    float s = (red[0][i] + red[1][i]) + (red[2][i] + red[3][i]);
    part[(size_t)(i >> 4) * D + lr + (i & 15)] = s;
  }
}

// ---------------- K3: fused minmax + Z + finalize + partition --------------
// grid 512: b = bx>>4, jc = bx&15 (128 j). 512 threads: thread t handles
// j = jc*128 + (t&127), i-quarter ih = t>>7. Stages q (=sum parts + bq) in
// LDS with in-flight minmax; Z via 4-way LDS combine; t<128 finalizes d_j,
// sign-partitions into block-private kdp segment via LDS counters.
__global__ __launch_bounds__(512, 4) void k3_dz(float* __restrict__ ws,
                                                const float* __restrict__ bq,
                                                const float* __restrict__ bk,
                                                const float* __restrict__ bv) {
  __shared__ float qs[2048];
  __shared__ float zs[512];
  __shared__ float rmx[8], rmn[8];
  __shared__ int cnt[2];
  const int bx = blockIdx.x, t = threadIdx.x;
  const int b = bx >> 4, jc = bx & 15;
  if (t == 0) { cnt[0] = 0; cnt[1] = 0; }

  // stage q = sum of 8 parts + bq (4 floats/thread) + minmax
  const size_t qb = (size_t)b * D;
  float4 bb = ((const float4*)bq)[t];
  float4 qv = bb;
#pragma unroll
  for (int p = 0; p < NPART; ++p) {
    float4 pp = ((const float4*)(ws + (size_t)p * PART_STRIDE + qb))[t];
    qv.x += pp.x; qv.y += pp.y; qv.z += pp.z; qv.w += pp.w;
  }
  *(float4*)&qs[t * 4] = qv;
  float mx = fmaxf(fmaxf(qv.x, qv.y), fmaxf(qv.z, qv.w));
  float mn = fminf(fminf(qv.x, qv.y), fminf(qv.z, qv.w));
#pragma unroll
  for (int off = 32; off; off >>= 1) {
    mx = fmaxf(mx, __shfl_down(mx, off));
    mn = fminf(mn, __shfl_down(mn, off));
  }
  if ((t & 63) == 0) { rmx[t >> 6] = mx; rmn[t >> 6] = mn; }
  __syncthreads();
  mx = rmx[0]; mn = rmn[0];
#pragma unroll
  for (int w = 1; w < 8; ++w) {
    mx = fmaxf(mx, rmx[w]);
    mn = fminf(mn, rmn[w]);
  }

  const int jl = t & 127, ih = t >> 7;
  const int j = jc * 128 + jl;
  const float k2 = (sum_parts(ws, 65536 + qb + j) + bk[j]) * L2E;
  const float m2 = (k2 >= 0.f) ? k2 * mx : k2 * mn;
  const float nm2 = -m2;
  const float* qp = qs + ih * 512;
  float z0 = 0.f, z1 = 0.f, z2 = 0.f, z3 = 0.f;
#pragma unroll 8
  for (int i = 0; i < 512; i += 4) {
    float4 q4 = *(const float4*)&qp[i];  // wave-uniform addr -> LDS broadcast
    z0 += fast_exp2(fmaf(q4.x, k2, nm2));
    z1 += fast_exp2(fmaf(q4.y, k2, nm2));
    z2 += fast_exp2(fmaf(q4.z, k2, nm2));
    z3 += fast_exp2(fmaf(q4.w, k2, nm2));
  }
  zs[t] = (z0 + z1) + (z2 + z3);
  __syncthreads();

  float2* kdp = (float2*)(ws + KDP_OFF) + ((size_t)b * 16 + jc) * SEG;
  if (t < 128) {
    float Z = (zs[t] + zs[t + 128]) + (zs[t + 256] + zs[t + 384]);
    float v = sum_parts(ws, 131072 + qb + j) + bv[j];
    float d = __log2f(fabsf(v) / Z) - m2;  // v==0 -> -inf -> exp2 -> 0
    int slot;
    if (v >= 0.f) slot = atomicAdd(&cnt[0], 1);
    else          slot = (SEG - 1) - atomicAdd(&cnt[1], 1);
    kdp[slot] = make_float2(k2, d);
  }
  __syncthreads();
  const int npos = cnt[0];
  if (t < 4) kdp[npos + t] = make_float2(0.f, -1e30f);  // gap pads: 0
  if (t == 0) ((int*)(ws + NP_OFF))[b * 16 + jc] = npos;
}

// ---------------- K4: out_i, plain store ----------------
// grid 512: b = bx>>4, ic = bx&15 (128 i). 512 threads: thread t handles
// i = ic*128 + (t&127), seg-quarter jh = t>>7 (4 of 16 segments). Stages
// the whole per-batch kdp (2112 float2 = 1056 float4, strided loop) +
// npos[16]; 4-way LDS combine; t<128 stores out directly (single writer).
__global__ __launch_bounds__(512, 4) void k4_out(const float* __restrict__ ws,
                                                 const float* __restrict__ bq,
                                                 float* __restrict__ out) {
  __shared__ float2 kd[16 * SEG];
  __shared__ int np[16];
  __shared__ float rs[512];
  const int bx = blockIdx.x, t = threadIdx.x;
  const int b = bx >> 4, ic = bx & 15;

  const float4* src = (const float4*)((const float2*)(ws + KDP_OFF) +
                                      (size_t)b * 16 * SEG);
  for (int idx = t; idx < (16 * SEG) / 2; idx += 512)
    ((float4*)kd)[idx] = src[idx];
  if (t < 16) np[t] = ((const int*)(ws + NP_OFF))[b * 16 + t];

  const int il = t & 127, jh = t >> 7;
  const int i = ic * 128 + il;
  const size_t io = (size_t)b * D + i;
  const float qi = sum_parts(ws, io) + bq[i];
  __syncthreads();

  float p0 = 0.f, p1 = 0.f, p2 = 0.f, p3 = 0.f;
  float n0 = 0.f, n1 = 0.f, n2 = 0.f, n3 = 0.f;
#pragma unroll
  for (int s = jh * 4; s < jh * 4 + 4; ++s) {
    const float2* seg = kd + s * SEG;
    const int npos = np[s];
    const int pe = (npos + 3) & ~3;      // pads beyond npos contribute 0
    const int ns = (npos + 4) & ~3;      // gap entries contribute 0
    for (int jj = 0; jj < pe; jj += 4) {
      float4 t0 = *(const float4*)&seg[jj];
      float4 t1 = *(const float4*)&seg[jj + 2];
      p0 += fast_exp2(fmaf(qi, t0.x, t0.y));
      p1 += fast_exp2(fmaf(qi, t0.z, t0.w));
      p2 += fast_exp2(fmaf(qi, t1.x, t1.y));
      p3 += fast_exp2(fmaf(qi, t1.z, t1.w));
    }
    for (int jj = ns; jj < SEG; jj += 4) {
      float4 t0 = *(const float4*)&seg[jj];
      float4 t1 = *(const float4*)&seg[jj + 2];
      n0 += fast_exp2(fmaf(qi, t0.x, t0.y));
      n1 += fast_exp2(fmaf(qi, t0.z, t0.w));
      n2 += fast_exp2(fmaf(qi, t1.x, t1.y));
      n3 += fast_exp2(fmaf(qi, t1.z, t1.w));
    }
  }
  rs[t] = ((p0 + p1) + (p2 + p3)) - ((n0 + n1) + (n2 + n3));
  __syncthreads();
  if (t < 128)
    out[io] = (rs[il] + rs[il + 128]) + (rs[il + 256] + rs[il + 384]);
}

extern "C" void kernel_launch(void* const* d_in, const int* in_sizes, int n_in,
                              void* d_out, int out_size, void* d_ws, size_t ws_size,
                              hipStream_t stream) {
  (void)in_sizes; (void)n_in; (void)out_size; (void)ws_size;
  const float* x  = (const float*)d_in[0];
  const float* Wq = (const float*)d_in[1];
  const float* bq = (const float*)d_in[2];
  const float* Wk = (const float*)d_in[3];
  const float* bk = (const float*)d_in[4];
  const float* Wv = (const float*)d_in[5];
  const float* bv = (const float*)d_in[6];
  float* ws  = (float*)d_ws;
  float* out = (float*)d_out;

  k1_proj<<<3072, 256, 0, stream>>>(x, Wq, Wk, Wv, ws);
  k3_dz<<<512, 512, 0, stream>>>(ws, bq, bk, bv);
  k4_out<<<512, 512, 0, stream>>>(ws, bq, out);
}

// Round 11
// 141.700 us; speedup vs baseline: 5.1503x; 1.0184x over previous
//
#include <hip/hip_runtime.h>
#include <math.h>

// B=32, D=2048 rank-1 self-attention, fp32.
//   k2_j = k_j*log2e ; m2_j = k2_j>=0 ? k2_j*qmax : k2_j*qmin
//   Z_j  = sum_i 2^(q_i k2_j - m2_j) ; d_j = log2(|v_j|/Z_j) - m2_j
//   out_i = sum_{j:v>0} 2^(fma(q_i,k2_j,d_j)) - sum_{j:v<0} 2^(...)
//
// R11: latency-exposure sweep on all three kernels.
//  k1: splitK=4, bounds(256,2) (VGPR 256) + FULL 24-float4 register prefetch
//      -> one vmcnt drain per wave (was 4); per-CU issued bytes >> port BW
//      need -> W stream at port limit (~10B/cyc/CU), k1 ~8-12us.
//  k3/k4: grid 1024 (4 blocks/CU), bounds(512,8) (VGPR<=64) -> 32 waves/CU
//      (was 16) to overlap the ~60cyc/iter ds_read+fma+exp2+add chain.
// No atomics, nothing pre-zeroed. Partition segs: 32 per batch, 68 slots.

#define D 2048
#define BATCH 32
#define SEGF 68       // kdp segment: 64 entries + 4 pad slots
#define NPART 4

// workspace float offsets
#define PART_STRIDE 196608   // one splitK part: 3*65536 (m*65536 + b*D + r)
#define KDP_OFF 786432       // 32 b * 32 segs * 68 float2 = 139264 floats
#define NP_OFF  925696       // 1024 ints: npos per (batch,seg)

#define L2E 1.4426950408889634f

typedef short s16x8 __attribute__((ext_vector_type(8)));
typedef float f32x4 __attribute__((ext_vector_type(4)));

union FragU { s16x8 v; unsigned u[4]; };

__device__ __forceinline__ float fast_exp2(float x) {
#if __has_builtin(__builtin_amdgcn_exp2f)
  return __builtin_amdgcn_exp2f(x);
#else
  return exp2f(x);
#endif
}
// pack two fp32 into one VGPR of two RNE-rounded bf16
__device__ __forceinline__ unsigned pack_rne(float a, float b) {
  unsigned ua = __float_as_uint(a), ub = __float_as_uint(b);
  ua = ua + 0x7FFFu + ((ua >> 16) & 1u);
  ub = ub + 0x7FFFu + ((ub >> 16) & 1u);
  return (ua >> 16) | (ub & 0xFFFF0000u);
}
__device__ __forceinline__ void pack8(const float4& fa, const float4& fb,
                                      FragU& h) {
  h.u[0] = pack_rne(fa.x, fa.y);
  h.u[1] = pack_rne(fa.z, fa.w);
  h.u[2] = pack_rne(fb.x, fb.y);
  h.u[3] = pack_rne(fb.z, fb.w);
}
// sum the 4 splitK partials at float offset o
__device__ __forceinline__ float sum_parts(const float* __restrict__ ws,
                                           size_t o) {
  float s0 = ws[o] + ws[o + PART_STRIDE];
  float s1 = ws[o + 2 * PART_STRIDE] + ws[o + 3 * PART_STRIDE];
  return s0 + s1;
}

// ---------------- K1: projections via LDS-free bf16 MFMA -------------------
// grid 1536 = 384 row-tiles(16 rows) x 4 K-quarters. 4 waves/block, wave wv
// covers K [kq*512 + wv*128, +128), 4 steps of 32. ALL 24 float4 (W + x)
// prefetched to registers before any pack/MFMA -> single vmcnt drain.
// A-frag = 8 consecutive fp32 of W per lane; B = 8 fp32 of x (batch lane&15
// / +16). RNE bf16, 2 MFMAs/step. LDS reduce, plain store to part kq.
__global__ __launch_bounds__(256, 2) void k1_proj(
    const float* __restrict__ x, const float* __restrict__ Wq,
    const float* __restrict__ Wk, const float* __restrict__ Wv,
    float* __restrict__ ws) {
  __shared__ float red[4][512];
  const int tid = threadIdx.x;
  const int lane = tid & 63, wv = tid >> 6;
  const int tile = blockIdx.x >> 2, kq = blockIdx.x & 3;
  const int m = tile >> 7, lr = (tile & 127) * 16;
  const float* W = (m == 0) ? Wq : (m == 1) ? Wk : Wv;

  const int kbase = kq * 512 + wv * 128 + (lane >> 4) * 8;
  const float* ap = W + (size_t)(lr + (lane & 15)) * D + kbase;
  const float* xp0 = x + (size_t)(lane & 15) * D + kbase;
  const float* xp1 = xp0 + 16 * D;

  float4 fa[4], fb[4], x0a[4], x0b[4], x1a[4], x1b[4];
#pragma unroll
  for (int s = 0; s < 4; ++s) {          // issue all 24 loads back-to-back
    const int off = s * 32;
    fa[s] = *(const float4*)(ap + off);
    fb[s] = *(const float4*)(ap + off + 4);
    x0a[s] = *(const float4*)(xp0 + off);
    x0b[s] = *(const float4*)(xp0 + off + 4);
    x1a[s] = *(const float4*)(xp1 + off);
    x1b[s] = *(const float4*)(xp1 + off + 4);
  }

  f32x4 acc0 = {0.f, 0.f, 0.f, 0.f}, acc1 = {0.f, 0.f, 0.f, 0.f};
#pragma unroll
  for (int s = 0; s < 4; ++s) {
    FragU Ah, Bh0, Bh1;
    pack8(fa[s], fb[s], Ah);
    pack8(x0a[s], x0b[s], Bh0);
    pack8(x1a[s], x1b[s], Bh1);
    acc0 = __builtin_amdgcn_mfma_f32_16x16x32_bf16(Ah.v, Bh0.v, acc0, 0, 0, 0);
    acc1 = __builtin_amdgcn_mfma_f32_16x16x32_bf16(Ah.v, Bh1.v, acc1, 0, 0, 0);
  }
  // C/D: col = lane&15 (batch), row = (lane>>4)*4 + reg (weight row)
  const int col = lane & 15, rq = (lane >> 4) * 4;
#pragma unroll
  for (int r = 0; r < 4; ++r) {
    red[wv][col * 16 + rq + r] = acc0[r];
    red[wv][(col + 16) * 16 + rq + r] = acc1[r];
  }
  __syncthreads();
  float* part = ws + (size_t)kq * PART_STRIDE + (size_t)m * 65536;
#pragma unroll
  for (int i = tid; i < 512; i += 256) {
    float s = (red[0][i] + red[1][i]) + (red[2][i] + red[3][i]);
    part[(size_t)(i >> 4) * D + lr + (i & 15)] = s;
  }
}

// ---------------- K3: fused minmax + Z + finalize + partition --------------
// grid 1024: b = bx>>5, jc = bx&31 (64 j). 512 threads: thread t handles
// j = jc*64 + (t&63), i-eighth ih = t>>6 (256 i each). Stages q (=sum parts
// + bq) in LDS with in-flight minmax; Z via 8-way LDS combine; t<64
// finalizes d_j, sign-partitions into block-private kdp seg via LDS counters.
__global__ __launch_bounds__(512, 8) void k3_dz(float* __restrict__ ws,
                                                const float* __restrict__ bq,
                                                const float* __restrict__ bk,
                                                const float* __restrict__ bv) {
  __shared__ float qs[2048];
  __shared__ float zs[512];
  __shared__ float rmx[8], rmn[8];
  __shared__ int cnt[2];
  const int bx = blockIdx.x, t = threadIdx.x;
  const int b = bx >> 5, jc = bx & 31;
  if (t == 0) { cnt[0] = 0; cnt[1] = 0; }

  // stage q = sum of 4 parts + bq (4 floats/thread) + minmax
  const size_t qb = (size_t)b * D;
  float4 p0 = ((const float4*)(ws + qb))[t];
  float4 p1 = ((const float4*)(ws + PART_STRIDE + qb))[t];
  float4 p2 = ((const float4*)(ws + 2 * PART_STRIDE + qb))[t];
  float4 p3 = ((const float4*)(ws + 3 * PART_STRIDE + qb))[t];
  float4 bb = ((const float4*)bq)[t];
  float4 qv = {(p0.x + p1.x) + (p2.x + p3.x) + bb.x,
               (p0.y + p1.y) + (p2.y + p3.y) + bb.y,
               (p0.z + p1.z) + (p2.z + p3.z) + bb.z,
               (p0.w + p1.w) + (p2.w + p3.w) + bb.w};
  *(float4*)&qs[t * 4] = qv;
  float mx = fmaxf(fmaxf(qv.x, qv.y), fmaxf(qv.z, qv.w));
  float mn = fminf(fminf(qv.x, qv.y), fminf(qv.z, qv.w));
#pragma unroll
  for (int off = 32; off; off >>= 1) {
    mx = fmaxf(mx, __shfl_down(mx, off));
    mn = fminf(mn, __shfl_down(mn, off));
  }
  if ((t & 63) == 0) { rmx[t >> 6] = mx; rmn[t >> 6] = mn; }
  __syncthreads();
  mx = rmx[0]; mn = rmn[0];
#pragma unroll
  for (int w = 1; w < 8; ++w) {
    mx = fmaxf(mx, rmx[w]);
    mn = fminf(mn, rmn[w]);
  }

  const int jl = t & 63, ih = t >> 6;
  const int j = jc * 64 + jl;
  const float k2 = (sum_parts(ws, 65536 + qb + j) + bk[j]) * L2E;
  const float m2 = (k2 >= 0.f) ? k2 * mx : k2 * mn;
  const float nm2 = -m2;
  const float* qp = qs + ih * 256;
  float z0 = 0.f, z1 = 0.f, z2 = 0.f, z3 = 0.f;
#pragma unroll 8
  for (int i = 0; i < 256; i += 4) {
    float4 q4 = *(const float4*)&qp[i];  // wave-uniform addr -> LDS broadcast
    z0 += fast_exp2(fmaf(q4.x, k2, nm2));
    z1 += fast_exp2(fmaf(q4.y, k2, nm2));
    z2 += fast_exp2(fmaf(q4.z, k2, nm2));
    z3 += fast_exp2(fmaf(q4.w, k2, nm2));
  }
  zs[t] = (z0 + z1) + (z2 + z3);
  __syncthreads();

  float2* kdp = (float2*)(ws + KDP_OFF) + ((size_t)b * 32 + jc) * SEGF;
  if (t < 64) {
    float Z = ((zs[t] + zs[t + 64]) + (zs[t + 128] + zs[t + 192])) +
              ((zs[t + 256] + zs[t + 320]) + (zs[t + 384] + zs[t + 448]));
    float v = sum_parts(ws, 131072 + qb + j) + bv[j];
    float d = __log2f(fabsf(v) / Z) - m2;  // v==0 -> -inf -> exp2 -> 0
    int slot;
    if (v >= 0.f) slot = atomicAdd(&cnt[0], 1);
    else          slot = (SEGF - 1) - atomicAdd(&cnt[1], 1);
    kdp[slot] = make_float2(k2, d);
  }
  __syncthreads();
  const int npos = cnt[0];
  if (t < 4) kdp[npos + t] = make_float2(0.f, -1e30f);  // gap pads: 0
  if (t == 0) ((int*)(ws + NP_OFF))[b * 32 + jc] = npos;
}

// ---------------- K4: out_i, plain store ----------------
// grid 1024: b = bx>>5, ic = bx&31 (64 i). 512 threads: thread t handles
// i = ic*64 + (t&63), seg-eighth jh = t>>6 (4 of 32 segments). Stages the
// whole per-batch kdp (2176 float2 = 1088 float4, strided) + npos[32];
// 8-way LDS combine; t<64 stores out directly (single writer).
__global__ __launch_bounds__(512, 8) void k4_out(const float* __restrict__ ws,
                                                 const float* __restrict__ bq,
                                                 float* __restrict__ out) {
  __shared__ float2 kd[32 * SEGF];
  __shared__ int np[32];
  __shared__ float rs[512];
  const int bx = blockIdx.x, t = threadIdx.x;
  const int b = bx >> 5, ic = bx & 31;

  const float4* src = (const float4*)((const float2*)(ws + KDP_OFF) +
                                      (size_t)b * 32 * SEGF);
  for (int idx = t; idx < (32 * SEGF) / 2; idx += 512)
    ((float4*)kd)[idx] = src[idx];
  if (t < 32) np[t] = ((const int*)(ws + NP_OFF))[b * 32 + t];

  const int il = t & 63, jh = t >> 6;
  const int i = ic * 64 + il;
  const size_t io = (size_t)b * D + i;
  const float qi = sum_parts(ws, io) + bq[i];
  __syncthreads();

  float p0 = 0.f, p1 = 0.f, p2 = 0.f, p3 = 0.f;
  float n0 = 0.f, n1 = 0.f, n2 = 0.f, n3 = 0.f;
#pragma unroll
  for (int s = jh * 4; s < jh * 4 + 4; ++s) {
    const float2* seg = kd + s * SEGF;
    const int npos = np[s];
    const int pe = (npos + 3) & ~3;      // pads beyond npos contribute 0
    const int ns = (npos + 4) & ~3;      // gap entries contribute 0
    for (int jj = 0; jj < pe; jj += 4) {
      float4 t0 = *(const float4*)&seg[jj];
      float4 t1 = *(const float4*)&seg[jj + 2];
      p0 += fast_exp2(fmaf(qi, t0.x, t0.y));
      p1 += fast_exp2(fmaf(qi, t0.z, t0.w));
      p2 += fast_exp2(fmaf(qi, t1.x, t1.y));
      p3 += fast_exp2(fmaf(qi, t1.z, t1.w));
    }
    for (int jj = ns; jj < SEGF; jj += 4) {
      float4 t0 = *(const float4*)&seg[jj];
      float4 t1 = *(const float4*)&seg[jj + 2];
      n0 += fast_exp2(fmaf(qi, t0.x, t0.y));
      n1 += fast_exp2(fmaf(qi, t0.z, t0.w));
      n2 += fast_exp2(fmaf(qi, t1.x, t1.y));
      n3 += fast_exp2(fmaf(qi, t1.z, t1.w));
    }
  }
  rs[t] = ((p0 + p1) + (p2 + p3)) - ((n0 + n1) + (n2 + n3));
  __syncthreads();
  if (t < 64)
    out[io] = ((rs[il] + rs[il + 64]) + (rs[il + 128] + rs[il + 192])) +
              ((rs[il + 256] + rs[il + 320]) + (rs[il + 384] + rs[il + 448]));
}

extern "C" void kernel_launch(void* const* d_in, const int* in_sizes, int n_in,
                              void* d_out, int out_size, void* d_ws, size_t ws_size,
                              hipStream_t stream) {
  (void)in_sizes; (void)n_in; (void)out_size; (void)ws_size;
  const float* x  = (const float*)d_in[0];
  const float* Wq = (const float*)d_in[1];
  const float* bq = (const float*)d_in[2];
  const float* Wk = (const float*)d_in[3];
  const float* bk = (const float*)d_in[4];
  const float* Wv = (const float*)d_in[5];
  const float* bv = (const float*)d_in[6];
  float* ws  = (float*)d_ws;
  float* out = (float*)d_out;

  k1_proj<<<1536, 256, 0, stream>>>(x, Wq, Wk, Wv, ws);
  k3_dz<<<1024, 512, 0, stream>>>(ws, bq, bk, bv);
  k4_out<<<1024, 512, 0, stream>>>(ws, bq, out);
}